// Round 12
// baseline (276.281 us; speedup 1.0000x reference)
//
#include <hip/hip_runtime.h>

#define NN 50000
#define EE 800000
#define FF 128
#define HH 4
#define BB 8
#define NEG 0.2f
#define NBLK ((NN + 255) / 256)   // 196

typedef __attribute__((ext_vector_type(8))) short s8v;
typedef __attribute__((ext_vector_type(4))) float f4v;

__device__ __forceinline__ unsigned short f2b(float f) {
    union { float f; unsigned u; } v; v.f = f;
    unsigned r = v.u + 0x7fffu + ((v.u >> 16) & 1u);
    return (unsigned short)(r >> 16);
}
__device__ __forceinline__ float b2f(unsigned short h) {
    union { unsigned u; float f; } v; v.u = ((unsigned)h) << 16;
    return v.f;
}
__device__ __forceinline__ float uasf(unsigned u) {
    union { unsigned u; float f; } v; v.u = u; return v.f;
}
__device__ __forceinline__ float lrelu(float t) { return t > 0.f ? t : NEG * t; }
__device__ __forceinline__ s8v cvt8(const float* p) {
    float4 f0 = *(const float4*)p;
    float4 f1 = *(const float4*)(p + 4);
    unsigned short u[8] = { f2b(f0.x), f2b(f0.y), f2b(f0.z), f2b(f0.w),
                            f2b(f1.x), f2b(f1.y), f2b(f1.z), f2b(f1.w) };
    return *(const s8v*)u;
}

// ---------------- prep: weight transpose/convert + cur=1 + pooled=0 ----------------
__global__ void k_prep(const float* __restrict__ locW, const float* __restrict__ regW,
                       const float* __restrict__ W1, const float* __restrict__ W2,
                       unsigned short* __restrict__ Wt, unsigned short* __restrict__ W1t,
                       unsigned short* __restrict__ W2t, int* cur, float* pooled) {
    int i = blockIdx.x * 256 + threadIdx.x;
    if (i < 32768) {
        int n = i >> 7, k = i & 127;
        float v = n < 128 ? locW[k * 128 + n] : regW[k * 128 + n - 128];
        Wt[i] = f2b(v);
    } else if (i < 131072) {
        int j = i - 32768; int n = j / 384, k = j - n * 384;
        W1t[j] = f2b(W1[k * 256 + n]);
    } else if (i < 163840) {
        int j = i - 131072; int n = j >> 8, k = j & 255;
        W2t[j] = f2b(W2[k * 128 + n]);
    } else {
        int j = i - 163840;
        if (j < NN) cur[j] = 1;
        if (j < BB * FF) pooled[j] = 0.f;
    }
}

// ---------------- count in-degree ----------------
__global__ void k_count(const int* __restrict__ ei, int* cur) {
    int i = blockIdx.x * 256 + threadIdx.x;
    if (i < EE) atomicAdd(&cur[ei[EE + i]], 1);
}

// ---------------- parallel scan: A (per-block), C (offset + self-loop placement) ----------------
__global__ __launch_bounds__(256) void k_scanA(int* cur, int* row_ptr, int* bsum) {
    __shared__ int wsum[4];
    int b = blockIdx.x, t = threadIdx.x;
    int i = b * 256 + t;
    int v = (i < NN) ? cur[i] : 0;
    if (i < NN) cur[i] = 0;
    int lane = t & 63, w = t >> 6;
    int sc = v;
#pragma unroll
    for (int off = 1; off < 64; off <<= 1) {
        int n = __shfl_up(sc, off);
        if (lane >= off) sc += n;
    }
    if (lane == 63) wsum[w] = sc;
    __syncthreads();
    int woff = 0;
    for (int k = 0; k < w; k++) woff += wsum[k];
    int incl = sc + woff;
    if (i < NN) row_ptr[i + 1] = incl;
    if (t == 255) bsum[b] = incl;
    if (i == 0) row_ptr[0] = 0;
}

__global__ __launch_bounds__(256) void k_scanC(int* row_ptr, const int* __restrict__ bsum,
                                               int* __restrict__ col) {
    __shared__ int ssum[4];
    int b = blockIdx.x, t = threadIdx.x;
    int lane = t & 63, w = t >> 6;
    int v = (t < b) ? bsum[t] : 0;   // b <= 195 < 256
#pragma unroll
    for (int off = 32; off; off >>= 1) v += __shfl_xor(v, off);
    if (lane == 0) ssum[w] = v;
    __syncthreads();
    int off = ssum[0] + ssum[1] + ssum[2] + ssum[3];
    int i = b * 256 + t;
    if (i < NN) {
        int fin = row_ptr[i + 1] + (b > 0 ? off : 0);
        if (b > 0) row_ptr[i + 1] = fin;
        col[fin - 1] = i;          // self-loop in the node's last slot
    }
}

// ---------------- scatter edges into CSR (slots 0..deg_edges-1) ----------------
__global__ void k_scatter(const int* __restrict__ ei, const int* __restrict__ row_ptr,
                          int* cur, int* col) {
    int i = blockIdx.x * 256 + threadIdx.x;
    if (i < EE) {
        int s = ei[i], d = ei[EE + i];
        int p = atomicAdd(&cur[d], 1);
        col[row_ptr[d] + p] = s;
    }
}

// ---------------- GEMM1 (MFMA, dbuf LDS): h -> hl/hr; alpha -> alc; fused pooling ----------------
__global__ __launch_bounds__(256) void k_gemm1(
    const float* __restrict__ x, const int* __restrict__ batch,
    const unsigned short* __restrict__ Wt,
    const float* __restrict__ loc_as, const float* __restrict__ loc_ad,
    const float* __restrict__ reg_as, const float* __restrict__ reg_ad,
    unsigned short* __restrict__ hl, unsigned short* __restrict__ hr,
    float* __restrict__ alc_s, float* __restrict__ alc_d,
    float* __restrict__ pooled) {
    __shared__ __align__(16) unsigned short SA[2][2048];
    __shared__ __align__(16) unsigned short SB[2][8192];
    __shared__ __align__(16) unsigned short Hs[16384];
    int t = threadIdx.x;
    int w = t >> 6, l = t & 63;
    int lq = l >> 4, lr = l & 15;
    int r0 = blockIdx.x * 64;

    int srow = t >> 2, sg = t & 3;
    int snode = r0 + srow; if (snode >= NN) snode = NN - 1;
    const float* xrow = x + (size_t)snode * 128 + sg * 8;

    f4v acc[4][4];
#pragma unroll
    for (int a0 = 0; a0 < 4; a0++)
#pragma unroll
        for (int b0 = 0; b0 < 4; b0++) acc[a0][b0] = (f4v){0.f, 0.f, 0.f, 0.f};

    *(s8v*)&SA[0][(sg * 64 + srow) * 8] = cvt8(xrow);
#pragma unroll
    for (int it = 0; it < 4; ++it) {
        int c = t + it * 256;
        int g = c & 3, n = c >> 2;
        *(s8v*)&SB[0][(g * 256 + n) * 8] = *(const s8v*)&Wt[(size_t)n * 128 + g * 8];
    }
    __syncthreads();
#pragma unroll
    for (int ks = 0; ks < 4; ++ks) {
        int cur = ks & 1;
        s8v pa; s8v pb[4];
        if (ks < 3) {
            pa = cvt8(xrow + (ks + 1) * 32);
#pragma unroll
            for (int it = 0; it < 4; ++it) {
                int c = t + it * 256;
                int g = c & 3, n = c >> 2;
                pb[it] = *(const s8v*)&Wt[(size_t)n * 128 + (ks + 1) * 32 + g * 8];
            }
        }
        s8v af[4], bf[4];
#pragma unroll
        for (int rf = 0; rf < 4; ++rf) af[rf] = *(const s8v*)&SA[cur][(lq * 64 + rf * 16 + lr) * 8];
#pragma unroll
        for (int cf = 0; cf < 4; ++cf) bf[cf] = *(const s8v*)&SB[cur][(lq * 256 + w * 64 + cf * 16 + lr) * 8];
#pragma unroll
        for (int rf = 0; rf < 4; ++rf)
#pragma unroll
            for (int cf = 0; cf < 4; ++cf)
                acc[rf][cf] = __builtin_amdgcn_mfma_f32_16x16x32_bf16(af[rf], bf[cf], acc[rf][cf], 0, 0, 0);
        if (ks < 3) {
            *(s8v*)&SA[cur ^ 1][(sg * 64 + srow) * 8] = pa;
#pragma unroll
            for (int it = 0; it < 4; ++it) {
                int c = t + it * 256;
                int g = c & 3, n = c >> 2;
                *(s8v*)&SB[cur ^ 1][(g * 256 + n) * 8] = pb[it];
            }
        }
        __syncthreads();
    }
#pragma unroll
    for (int cf = 0; cf < 4; ++cf) {
        int c = w * 64 + cf * 16 + lr;
#pragma unroll
        for (int rf = 0; rf < 4; ++rf)
#pragma unroll
            for (int i = 0; i < 4; ++i) {
                int row = rf * 16 + lq * 4 + i;
                Hs[((c >> 3) * 64 + row) * 8 + (c & 7)] = f2b(acc[rf][cf][i]);
            }
    }
    __syncthreads();
#pragma unroll
    for (int it = 0; it < 8; ++it) {
        int c = t + it * 256;
        int row = c >> 5, g = c & 31;
        int node = r0 + row;
        if (node < NN) {
            s8v v = *(const s8v*)&Hs[(g * 64 + row) * 8];
            int cc = g * 8;
            if (cc < 128) *(s8v*)&hl[(size_t)node * 128 + cc] = v;
            else          *(s8v*)&hr[(size_t)node * 128 + cc - 128] = v;
        }
    }
#pragma unroll
    for (int it = 0; it < 4; ++it) {
        int row = it * 16 + (t >> 4);
        int node = r0 + row;
        int q = t & 15;
        int gat = q >> 3, sd = (q >> 2) & 1, head = q & 3;
        const float* av = gat ? (sd ? reg_ad : reg_as) : (sd ? loc_ad : loc_as);
        float s = 0.f;
        int cbase = gat * 128 + head * 32;
        for (int d = 0; d < 32; ++d) {
            int c = cbase + d;
            s += b2f(Hs[((c >> 3) * 64 + row) * 8 + (c & 7)]) * av[head * 32 + d];
        }
        if (node < NN) {
            float* outp = sd ? alc_d : alc_s;
            outp[(size_t)node * 8 + gat * 4 + head] = s;
        }
    }
    {
        int colp = t & 127, halfp = t >> 7;
        int rbase = r0 + halfp * 32;
        int lastrow = r0 + 63; if (lastrow >= NN) lastrow = NN - 1;
        int blo = batch[r0 < NN ? r0 : NN - 1];
        int bhi = batch[lastrow];
        float acc0 = 0.f, acc1 = 0.f;
        for (int r = 0; r < 32; ++r) {
            int row = rbase + r;
            if (row < NN) {
                float v = x[(size_t)row * 128 + colp];
                int b = batch[row];
                if (b == blo) acc0 += v; else acc1 += v;
            }
        }
        atomicAdd(&pooled[blo * 128 + colp], acc0);
        if (bhi != blo) atomicAdd(&pooled[bhi * 128 + colp], acc1);
    }
}

// ---------------- gfeat: one block per graph; also precompute gpre = g8 @ W1[256:384] ----------------
__global__ __launch_bounds__(256) void k_gfeat8(
    const float* __restrict__ pooled, const int* __restrict__ batch,
    const float* __restrict__ W1, const float* __restrict__ b1,
    const float* __restrict__ W2, const float* __restrict__ b2,
    const float* __restrict__ fuW1,
    float* __restrict__ gpre) {
    __shared__ float mean_s[128];
    __shared__ float hid_s[128];
    __shared__ float part[256];
    __shared__ float g8s[128];
    __shared__ int bnd[2];
    int b = blockIdx.x, t = threadIdx.x;
    if (t < 2) {
        int target = b + t;
        int lo = 0, hi = NN;
        while (lo < hi) { int mid = (lo + hi) >> 1; if (batch[mid] < target) lo = mid + 1; else hi = mid; }
        bnd[t] = lo;
    }
    __syncthreads();
    int cnt = bnd[1] - bnd[0];
    float inv = cnt ? 1.f / (float)cnt : 0.f;
    if (t < 128) mean_s[t] = pooled[b * 128 + t] * inv;
    __syncthreads();
    int c = t & 127, kh = t >> 7;
    float a = 0.f;
    for (int k = kh * 64; k < kh * 64 + 64; k++) a += mean_s[k] * W1[k * 128 + c];
    part[t] = a;
    __syncthreads();
    if (t < 128) hid_s[t] = fmaxf(part[t] + part[t + 128] + b1[t], 0.f);
    __syncthreads();
    float a2 = 0.f;
    for (int k = kh * 64; k < kh * 64 + 64; k++) a2 += hid_s[k] * W2[k * 128 + c];
    part[t] = a2;
    __syncthreads();
    if (t < 128) g8s[t] = part[t] + part[t + 128] + b2[t];
    __syncthreads();
    // gpre[b][t] = sum_k g8s[k] * fuW1[(256+k)*256 + t]   (t = 0..255)
    float a3 = 0.f;
    for (int k = 0; k < 128; k++) a3 += g8s[k] * fuW1[(size_t)(256 + k) * 256 + t];
    gpre[(size_t)b * 256 + t] = a3;
}

// ---------------- GAT aggregate (R5 structure, interleaved alc) ----------------
__global__ __launch_bounds__(256) void k_gat(
    const int* __restrict__ row_ptr, const int* __restrict__ col,
    const unsigned short* __restrict__ hl, const unsigned short* __restrict__ hr,
    const float* __restrict__ alc_s, const float* __restrict__ alc_d,
    const float* __restrict__ x,
    const float* __restrict__ loc_bias, const float* __restrict__ loc_g, const float* __restrict__ loc_b,
    const float* __restrict__ reg_bias, const float* __restrict__ reg_g, const float* __restrict__ reg_b,
    unsigned short* __restrict__ out_local, unsigned short* __restrict__ out_reg) {
    __shared__ float exA[4][64][4];
    __shared__ float exB[4][64][4];
    __shared__ int   colb[4][64];
    __shared__ int   degs[4];
    int w = threadIdx.x >> 6, lane = threadIdx.x & 63;
    int hA = lane >> 4;
    int node = blockIdx.x * 4 + w;
    int rp0 = row_ptr[node];
    int deg = row_ptr[node + 1] - rp0;
    if (lane == 0) degs[w] = deg;
    float4 adL = *(const float4*)&alc_d[(size_t)node * 8];
    float4 adR = *(const float4*)&alc_d[(size_t)node * 8 + 4];
    __syncthreads();
    int maxdeg = max(max(degs[0], degs[1]), max(degs[2], degs[3]));
    int chunks = (maxdeg + 63) >> 6;

    float sL0 = 0.f, sL1 = 0.f, sL2 = 0.f, sL3 = 0.f;
    float sR0 = 0.f, sR1 = 0.f, sR2 = 0.f, sR3 = 0.f;
    for (int base = 0; base < deg; base += 64) {
        int i = base + lane;
        bool v = i < deg;
        int s = col[rp0 + (v ? i : deg - 1)];
        float4 aL = *(const float4*)&alc_s[(size_t)s * 8];
        float4 aR = *(const float4*)&alc_s[(size_t)s * 8 + 4];
        float e0 = __expf(lrelu(aL.x + adL.x));
        float e1 = __expf(lrelu(aL.y + adL.y));
        float e2 = __expf(lrelu(aL.z + adL.z));
        float e3 = __expf(lrelu(aL.w + adL.w));
        float f0 = __expf(lrelu(aR.x + adR.x));
        float f1 = __expf(lrelu(aR.y + adR.y));
        float f2 = __expf(lrelu(aR.z + adR.z));
        float f3 = __expf(lrelu(aR.w + adR.w));
        if (!v) { e0 = e1 = e2 = e3 = f0 = f1 = f2 = f3 = 0.f; }
        *(float4*)&exA[w][lane][0] = make_float4(e0, e1, e2, e3);
        *(float4*)&exB[w][lane][0] = make_float4(f0, f1, f2, f3);
        colb[w][lane] = s;
        sL0 += e0; sL1 += e1; sL2 += e2; sL3 += e3;
        sR0 += f0; sR1 += f1; sR2 += f2; sR3 += f3;
    }
    __syncthreads();
#pragma unroll
    for (int off = 32; off; off >>= 1) {
        sL0 += __shfl_xor(sL0, off); sL1 += __shfl_xor(sL1, off);
        sL2 += __shfl_xor(sL2, off); sL3 += __shfl_xor(sL3, off);
        sR0 += __shfl_xor(sR0, off); sR1 += __shfl_xor(sR1, off);
        sR2 += __shfl_xor(sR2, off); sR3 += __shfl_xor(sR3, off);
    }
    float iA = (hA & 2) ? ((hA & 1) ? 1.f / sL3 : 1.f / sL2)
                        : ((hA & 1) ? 1.f / sL1 : 1.f / sL0);
    float iB = (hA & 2) ? ((hA & 1) ? 1.f / sR3 : 1.f / sR2)
                        : ((hA & 1) ? 1.f / sR1 : 1.f / sR0);

    float a0 = 0.f, a1 = 0.f, b0 = 0.f, b1 = 0.f;
    const unsigned* hlp = (const unsigned*)hl;
    const unsigned* hrp = (const unsigned*)hr;
    if (chunks == 1) {
#pragma unroll 4
        for (int e = 0; e < deg; ++e) {
            int s = colb[w][e];
            float eAv = exA[w][e][hA];
            float eBv = exB[w][e][hA];
            unsigned ul = hlp[(size_t)s * 64 + lane];
            unsigned ur = hrp[(size_t)s * 64 + lane];
            a0 += eAv * uasf(ul << 16);
            a1 += eAv * uasf(ul & 0xffff0000u);
            b0 += eBv * uasf(ur << 16);
            b1 += eBv * uasf(ur & 0xffff0000u);
        }
    } else {
        for (int c = 0; c < chunks; ++c) {
            int base = c * 64, i = base + lane;
            if (i < deg) {
                int s = col[rp0 + i];
                float4 aL = *(const float4*)&alc_s[(size_t)s * 8];
                float4 aR = *(const float4*)&alc_s[(size_t)s * 8 + 4];
                *(float4*)&exA[w][lane][0] = make_float4(
                    __expf(lrelu(aL.x + adL.x)), __expf(lrelu(aL.y + adL.y)),
                    __expf(lrelu(aL.z + adL.z)), __expf(lrelu(aL.w + adL.w)));
                *(float4*)&exB[w][lane][0] = make_float4(
                    __expf(lrelu(aR.x + adR.x)), __expf(lrelu(aR.y + adR.y)),
                    __expf(lrelu(aR.z + adR.z)), __expf(lrelu(aR.w + adR.w)));
                colb[w][lane] = s;
            }
            __syncthreads();
            int nc = deg - base; nc = nc < 0 ? 0 : (nc > 64 ? 64 : nc);
#pragma unroll 4
            for (int e = 0; e < nc; ++e) {
                int s = colb[w][e];
                float eAv = exA[w][e][hA];
                float eBv = exB[w][e][hA];
                unsigned ul = hlp[(size_t)s * 64 + lane];
                unsigned ur = hrp[(size_t)s * 64 + lane];
                a0 += eAv * uasf(ul << 16);
                a1 += eAv * uasf(ul & 0xffff0000u);
                b0 += eBv * uasf(ur << 16);
                b1 += eBv * uasf(ur & 0xffff0000u);
            }
            __syncthreads();
        }
    }

    int f = 2 * lane;
    float2 xr = *(const float2*)&x[(size_t)node * 128 + f];
    float2 lbi = *(const float2*)&loc_bias[f];
    float2 rbi = *(const float2*)&reg_bias[f];
    float v0 = a0 * iA + lbi.x + xr.x;
    float v1 = a1 * iA + lbi.y + xr.y;
    float u0 = b0 * iB + rbi.x + xr.x;
    float u1 = b1 * iB + rbi.y + xr.y;

    float sv = v0 + v1, su = u0 + u1;
#pragma unroll
    for (int off = 32; off; off >>= 1) { sv += __shfl_xor(sv, off); su += __shfl_xor(su, off); }
    float mv = sv * (1.f / 128.f), mu = su * (1.f / 128.f);
    float dv0 = v0 - mv, dv1 = v1 - mv, du0 = u0 - mu, du1 = u1 - mu;
    float qv = dv0 * dv0 + dv1 * dv1, qu = du0 * du0 + du1 * du1;
#pragma unroll
    for (int off = 32; off; off >>= 1) { qv += __shfl_xor(qv, off); qu += __shfl_xor(qu, off); }
    float rv = rsqrtf(qv * (1.f / 128.f) + 1e-5f), ru = rsqrtf(qu * (1.f / 128.f) + 1e-5f);
    float2 lg = *(const float2*)&loc_g[f], lb2 = *(const float2*)&loc_b[f];
    float2 rg = *(const float2*)&reg_g[f], rb2 = *(const float2*)&reg_b[f];
    unsigned pv = (unsigned)f2b(dv0 * rv * lg.x + lb2.x) | ((unsigned)f2b(dv1 * rv * lg.y + lb2.y) << 16);
    unsigned pu = (unsigned)f2b(du0 * ru * rg.x + rb2.x) | ((unsigned)f2b(du1 * ru * rg.y + rb2.y) << 16);
    *(unsigned*)&out_local[(size_t)node * 128 + f] = pv;
    *(unsigned*)&out_reg[(size_t)node * 128 + f]   = pu;
}

// ---------------- fused MLP (MFMA, dbuf LDS, K=256 + gpre hoist) ----------------
__global__ __launch_bounds__(256) void k_fusedm(
    const unsigned short* __restrict__ localb, const unsigned short* __restrict__ regionalb,
    const float* __restrict__ gpre, const int* __restrict__ batch,
    const unsigned short* __restrict__ W1t, const float* __restrict__ b1,
    const unsigned short* __restrict__ W2t, const float* __restrict__ b2,
    const float* __restrict__ lng, const float* __restrict__ lnb,
    float* __restrict__ out) {
    __shared__ __align__(16) unsigned short stg[20480];  // 40KB staging
    __shared__ __align__(16) unsigned short Hs[16384];   // 32KB hidden
    __shared__ int bS[64];
    unsigned short* SAb[2] = { stg, stg + 2048 };
    unsigned short* SBb[2] = { stg + 4096, stg + 12288 };
    unsigned short* W2Sb[2] = { stg, stg + 4096 };
    int t = threadIdx.x;
    int w = t >> 6, l = t & 63;
    int lq = l >> 4, lr = l & 15;
    int r0 = blockIdx.x * 64;

    int srow = t >> 2, sg = t & 3;
    int snode = r0 + srow; if (snode >= NN) snode = NN - 1;
    if (t < 64) {
        int n = r0 + t; if (n >= NN) n = NN - 1;
        bS[t] = batch[n];
    }

    auto asrc = [&](int ks) -> const unsigned short* {
        int seg = ks >> 2;
        int ko = (ks & 3) * 32 + sg * 8;
        return seg == 0 ? localb + (size_t)snode * 128 + ko :
                          regionalb + (size_t)snode * 128 + ko;
    };

    f4v acc[4][4];
#pragma unroll
    for (int a0 = 0; a0 < 4; a0++)
#pragma unroll
        for (int b0 = 0; b0 < 4; b0++) acc[a0][b0] = (f4v){0.f, 0.f, 0.f, 0.f};

    // prologue: stage ks=0
    *(s8v*)&SAb[0][(sg * 64 + srow) * 8] = *(const s8v*)asrc(0);
#pragma unroll
    for (int it = 0; it < 4; ++it) {
        int c = t + it * 256;
        int g = c & 3, n = c >> 2;
        *(s8v*)&SBb[0][(g * 256 + n) * 8] = *(const s8v*)&W1t[(size_t)n * 384 + g * 8];
    }
    __syncthreads();
#pragma unroll
    for (int ks = 0; ks < 8; ++ks) {
        int cur = ks & 1;
        s8v pa; s8v pb[4];
        if (ks < 7) {
            pa = *(const s8v*)asrc(ks + 1);
#pragma unroll
            for (int it = 0; it < 4; ++it) {
                int c = t + it * 256;
                int g = c & 3, n = c >> 2;
                pb[it] = *(const s8v*)&W1t[(size_t)n * 384 + (ks + 1) * 32 + g * 8];
            }
        }
        s8v af[4], bf[4];
#pragma unroll
        for (int rf = 0; rf < 4; ++rf) af[rf] = *(const s8v*)&SAb[cur][(lq * 64 + rf * 16 + lr) * 8];
#pragma unroll
        for (int cf = 0; cf < 4; ++cf) bf[cf] = *(const s8v*)&SBb[cur][(lq * 256 + w * 64 + cf * 16 + lr) * 8];
#pragma unroll
        for (int rf = 0; rf < 4; ++rf)
#pragma unroll
            for (int cf = 0; cf < 4; ++cf)
                acc[rf][cf] = __builtin_amdgcn_mfma_f32_16x16x32_bf16(af[rf], bf[cf], acc[rf][cf], 0, 0, 0);
        if (ks < 7) {
            *(s8v*)&SAb[cur ^ 1][(sg * 64 + srow) * 8] = pa;
#pragma unroll
            for (int it = 0; it < 4; ++it) {
                int c = t + it * 256;
                int g = c & 3, n = c >> 2;
                *(s8v*)&SBb[cur ^ 1][(g * 256 + n) * 8] = pb[it];
            }
        }
        __syncthreads();
    }
    // epilogue 1: bias + gpre[batch] + relu -> Hs (bf16)
#pragma unroll
    for (int cf = 0; cf < 4; ++cf) {
        int c = w * 64 + cf * 16 + lr;
        float bc = b1[c];
#pragma unroll
        for (int rf = 0; rf < 4; ++rf)
#pragma unroll
            for (int i = 0; i < 4; ++i) {
                int row = rf * 16 + lq * 4 + i;
                float v0 = acc[rf][cf][i] + bc + gpre[(size_t)bS[row] * 256 + c];
                Hs[((c >> 3) * 64 + row) * 8 + (c & 7)] = f2b(v0 > 0.f ? v0 : 0.f);
            }
    }
    __syncthreads();
#pragma unroll
    for (int it = 0; it < 2; ++it) {
        int c = t + it * 256;
        int g = c & 3, n = c >> 2;
        *(s8v*)&W2Sb[0][(g * 128 + n) * 8] = *(const s8v*)&W2t[(size_t)n * 256 + g * 8];
    }
    __syncthreads();
    f4v a2[8];
#pragma unroll
    for (int cf = 0; cf < 8; ++cf) a2[cf] = (f4v){0.f, 0.f, 0.f, 0.f};
#pragma unroll
    for (int ks = 0; ks < 8; ++ks) {
        int cur = ks & 1;
        s8v pw[2];
        if (ks < 7) {
#pragma unroll
            for (int it = 0; it < 2; ++it) {
                int c = t + it * 256;
                int g = c & 3, n = c >> 2;
                pw[it] = *(const s8v*)&W2t[(size_t)n * 256 + (ks + 1) * 32 + g * 8];
            }
        }
        s8v af = *(const s8v*)&Hs[((ks * 4 + lq) * 64 + w * 16 + lr) * 8];
#pragma unroll
        for (int cf = 0; cf < 8; ++cf) {
            s8v bfv = *(const s8v*)&W2Sb[cur][(lq * 128 + cf * 16 + lr) * 8];
            a2[cf] = __builtin_amdgcn_mfma_f32_16x16x32_bf16(af, bfv, a2[cf], 0, 0, 0);
        }
        if (ks < 7) {
#pragma unroll
            for (int it = 0; it < 2; ++it) {
                int c = t + it * 256;
                int g = c & 3, n = c >> 2;
                *(s8v*)&W2Sb[cur ^ 1][(g * 128 + n) * 8] = pw[it];
            }
        }
        __syncthreads();
    }
    float b2c[8], gc[8], bc2[8];
#pragma unroll
    for (int cf = 0; cf < 8; ++cf) {
        int c = cf * 16 + lr;
        b2c[cf] = b2[c]; gc[cf] = lng[c]; bc2[cf] = lnb[c];
    }
#pragma unroll
    for (int i = 0; i < 4; ++i) {
        int row = w * 16 + lq * 4 + i;
        int node = r0 + row;
        float vals[8]; float s = 0.f;
#pragma unroll
        for (int cf = 0; cf < 8; ++cf) { vals[cf] = a2[cf][i] + b2c[cf]; s += vals[cf]; }
        s += __shfl_xor(s, 1); s += __shfl_xor(s, 2); s += __shfl_xor(s, 4); s += __shfl_xor(s, 8);
        float mean = s * (1.f / 128.f);
        float vs = 0.f;
#pragma unroll
        for (int cf = 0; cf < 8; ++cf) { float d = vals[cf] - mean; vs += d * d; }
        vs += __shfl_xor(vs, 1); vs += __shfl_xor(vs, 2); vs += __shfl_xor(vs, 4); vs += __shfl_xor(vs, 8);
        float rstd = rsqrtf(vs * (1.f / 128.f) + 1e-5f);
        if (node < NN) {
#pragma unroll
            for (int cf = 0; cf < 8; ++cf)
                out[(size_t)node * 128 + cf * 16 + lr] = (vals[cf] - mean) * rstd * gc[cf] + bc2[cf];
        }
    }
}

extern "C" void kernel_launch(void* const* d_in, const int* in_sizes, int n_in,
                              void* d_out, int out_size, void* d_ws, size_t ws_size,
                              hipStream_t stream) {
    const float* x      = (const float*)d_in[0];
    const int*   ei     = (const int*)d_in[1];
    const int*   batch  = (const int*)d_in[2];
    const float* locW   = (const float*)d_in[3];
    const float* loc_as = (const float*)d_in[4];
    const float* loc_ad = (const float*)d_in[5];
    const float* loc_bi = (const float*)d_in[6];
    const float* loc_g  = (const float*)d_in[7];
    const float* loc_b  = (const float*)d_in[8];
    const float* regW   = (const float*)d_in[9];
    const float* reg_as = (const float*)d_in[10];
    const float* reg_ad = (const float*)d_in[11];
    const float* reg_bi = (const float*)d_in[12];
    const float* reg_g  = (const float*)d_in[13];
    const float* reg_b  = (const float*)d_in[14];
    const float* gp_W1  = (const float*)d_in[15];
    const float* gp_b1  = (const float*)d_in[16];
    const float* gp_W2  = (const float*)d_in[17];
    const float* gp_b2  = (const float*)d_in[18];
    const float* fu_W1  = (const float*)d_in[19];
    const float* fu_b1  = (const float*)d_in[20];
    const float* fu_W2  = (const float*)d_in[21];
    const float* fu_b2  = (const float*)d_in[22];
    const float* fu_lg  = (const float*)d_in[23];
    const float* fu_lb  = (const float*)d_in[24];
    float* out = (float*)d_out;

    char* ws = (char*)d_ws;
    size_t off = 0;
    auto alloc = [&](size_t bytes) { void* p = ws + off; off += (bytes + 255) & ~(size_t)255; return p; };
    unsigned short* hl        = (unsigned short*)alloc((size_t)NN * 128 * 2);
    unsigned short* hr        = (unsigned short*)alloc((size_t)NN * 128 * 2);
    unsigned short* localb    = (unsigned short*)alloc((size_t)NN * 128 * 2);
    unsigned short* regionalb = (unsigned short*)alloc((size_t)NN * 128 * 2);
    float* alc_s  = (float*)alloc((size_t)NN * 8 * 4);
    float* alc_d  = (float*)alloc((size_t)NN * 8 * 4);
    int* row_ptr  = (int*)alloc((size_t)(NN + 1) * 4);
    int* cur      = (int*)alloc((size_t)NN * 4);
    int* col      = (int*)alloc((size_t)(EE + NN) * 4);
    float* pooled = (float*)alloc((size_t)BB * 128 * 4);
    float* gpre   = (float*)alloc((size_t)BB * 256 * 4);
    unsigned short* Wt  = (unsigned short*)alloc((size_t)32768 * 2);
    unsigned short* W1t = (unsigned short*)alloc((size_t)98304 * 2);
    unsigned short* W2t = (unsigned short*)alloc((size_t)32768 * 2);
    int* bsum = (int*)alloc((size_t)NBLK * 4);

    hipLaunchKernelGGL(k_prep, dim3(640 + NBLK), dim3(256), 0, stream,
                       locW, regW, fu_W1, fu_W2, Wt, W1t, W2t, cur, pooled);
    hipLaunchKernelGGL(k_count, dim3((EE + 255) / 256), dim3(256), 0, stream, ei, cur);
    hipLaunchKernelGGL(k_scanA, dim3(NBLK), dim3(256), 0, stream, cur, row_ptr, bsum);
    hipLaunchKernelGGL(k_scanC, dim3(NBLK), dim3(256), 0, stream, row_ptr, bsum, col);
    hipLaunchKernelGGL(k_scatter, dim3((EE + 255) / 256), dim3(256), 0, stream, ei, row_ptr, cur, col);
    hipLaunchKernelGGL(k_gemm1, dim3((NN + 63) / 64), dim3(256), 0, stream,
                       x, batch, Wt, loc_as, loc_ad, reg_as, reg_ad,
                       hl, hr, alc_s, alc_d, pooled);
    hipLaunchKernelGGL(k_gfeat8, dim3(BB), dim3(256), 0, stream,
                       pooled, batch, gp_W1, gp_b1, gp_W2, gp_b2, fu_W1, gpre);
    hipLaunchKernelGGL(k_gat, dim3(NN / 4), dim3(256), 0, stream,
                       row_ptr, col, hl, hr, alc_s, alc_d, x,
                       loc_bi, loc_g, loc_b, reg_bi, reg_g, reg_b,
                       localb, regionalb);
    hipLaunchKernelGGL(k_fusedm, dim3((NN + 63) / 64), dim3(256), 0, stream,
                       localb, regionalb, gpre, batch,
                       W1t, fu_b1, W2t, fu_b2, fu_lg, fu_lb, out);
}